// Round 6
// baseline (176.675 us; speedup 1.0000x reference)
//
#include <hip/hip_runtime.h>

// ---------------------------------------------------------------------------
// MH-MoE, top-2 sparse dispatch, in-register expert FFN.
// B=2 S=2048 H=1024 NH=8 HD=128 T=16384 (32768 tokens) E=8 K=2 F=512
// FFN v6: F-split 8-wave blocks (waves 0-3: f[0,256), waves 4-7: f[256,512)),
// weights via global_load_lds double-buffer (1 barrier/iter, 8 iters),
// fp32 partial-y reduction through aliased LDS pool. Act stays in registers
// (cvt_pk_bf16 + permlane32_swap).
// ---------------------------------------------------------------------------

typedef __attribute__((ext_vector_type(8))) short bf16x8;
typedef __attribute__((ext_vector_type(4))) float f32x4;
typedef __attribute__((ext_vector_type(16))) float f32x16;
typedef __attribute__((ext_vector_type(4))) unsigned short u16x4;

constexpr int NSLOT = 66560;      // 520 tiles * 128 slots
constexpr int NTILE_MAX = 520;
#define CTRL_CNT 0
#define CTRL_CUR 8

__device__ __forceinline__ unsigned short f2bf(float x) {
  unsigned int u = __float_as_uint(x);
  return (unsigned short)((u + 0x7FFFu + ((u >> 16) & 1u)) >> 16);
}
__device__ __forceinline__ float bf2f(unsigned short u) {
  return __uint_as_float(((unsigned int)u) << 16);
}
__device__ __forceinline__ void gload_lds16(const void* g, void* l) {
  __builtin_amdgcn_global_load_lds(
      (const __attribute__((address_space(1))) unsigned int*)g,
      (__attribute__((address_space(3))) unsigned int*)l, 16, 0, 0);
}

// ---------------- fused prep (unchanged from r5) ----------------
__global__ __launch_bounds__(256) void prep_all(
    const float* __restrict__ x, unsigned short* __restrict__ x_bf,
    const float* __restrict__ Wmh, unsigned short* __restrict__ Wmh_t,
    const float* __restrict__ Wmg, unsigned short* __restrict__ Wmg_t,
    const float* __restrict__ W1, const float* __restrict__ W2,
    unsigned short* __restrict__ W1F, unsigned short* __restrict__ W2F,
    const float* __restrict__ bmh, const float* __restrict__ Wr,
    float* __restrict__ Wc, int* __restrict__ ctrl) {
  __shared__ float smem[2048];
  const int bid = blockIdx.x, tid = threadIdx.x;
  if (bid < 1024) {
    if (bid == 0 && tid < 16) ctrl[tid] = 0;
    int i = bid * 256 + tid;
    const int n4 = 4096 * 1024 / 4, stride = 1024 * 256;
    for (; i < n4; i += stride) {
      float4 v = ((const float4*)x)[i];
      u16x4 o;
      o.x = f2bf(v.x); o.y = f2bf(v.y); o.z = f2bf(v.z); o.w = f2bf(v.w);
      ((u16x4*)x_bf)[i] = o;
    }
  } else if (bid < 3072) {
    const int b = bid - 1024;
    const float* src = (b < 1024) ? Wmh : Wmg;
    unsigned short* dst = (b < 1024) ? Wmh_t : Wmg_t;
    const int bb = b & 1023;
    const int c0 = (bb & 31) * 32, r0 = (bb >> 5) * 32;
    const int tx = tid & 31, ty = tid >> 5;
    float (*tile)[33] = (float(*)[33])smem;
    for (int i = ty; i < 32; i += 8)
      tile[i][tx] = src[(size_t)(r0 + i) * 1024 + c0 + tx];
    __syncthreads();
    for (int i = ty; i < 32; i += 8)
      dst[(size_t)(c0 + i) * 1024 + r0 + tx] = f2bf(tile[tx][i]);
  } else if (bid < 3584) {
    const int jid = (bid - 3072) * 4 + (tid >> 6);   // 0..2047
    const int l = tid & 63;
    const int is2 = jid >= 1024;
    const int bj = is2 ? jid - 1024 : jid;
    const float* src;
    int C;
    if (!is2) {
      int kk = bj & 7, ft = (bj >> 3) & 15, e = bj >> 7;
      src = W1 + (size_t)e * 65536 + (size_t)(kk * 16) * 512 + ft * 32;
      C = 512;
    } else {
      int sht = bj & 7, ft = (bj >> 3) & 15, e = bj >> 7;
      src = W2 + (size_t)e * 65536 + (size_t)(ft * 32 + (sht >> 2) * 16) * 128 + (sht & 3) * 32;
      C = 128;
    }
    float* tile = smem + (tid >> 6) * 512;   // [16][32]
#pragma unroll
    for (int r = 0; r < 8; ++r) {
      int i = l + 64 * r;
      tile[(i >> 5) * 32 + (i & 31)] = src[(size_t)(i >> 5) * C + (i & 31)];
    }
    __syncthreads();
    int l31 = l & 31, lh = l >> 5;
    bf16x8 v;
#pragma unroll
    for (int j = 0; j < 8; ++j) v[j] = (short)f2bf(tile[(lh * 8 + j) * 32 + l31]);
    unsigned short* dst = is2 ? W2F : W1F;
    *(bf16x8*)(dst + ((size_t)bj * 64 + l) * 8) = v;
  } else {
    const int r = (bid - 3584) * 4 + (tid >> 6);
    if (r > 1024) return;
    const int l = tid & 63;
    const float* src = (r < 1024) ? (Wmh + (size_t)r * 1024) : bmh;
    int nh = l >> 3, e = l & 7;
    float acc = 0.f;
    for (int d = 0; d < 128; ++d) acc = fmaf(src[nh * 128 + d], Wr[d * 8 + e], acc);
    Wc[(size_t)r * 64 + l] = acc;
  }
}

// ---------------- router (unchanged) ----------------
__global__ __launch_bounds__(256) void router_kernel(
    const float* __restrict__ x, const float* __restrict__ Wc,
    int* __restrict__ tok_e, float* __restrict__ tok_g,
    int* __restrict__ ctrl, int* __restrict__ perm, float* __restrict__ gateb) {
  int gi = blockIdx.x * 256 + threadIdx.x;
  if (gi < NSLOT) { perm[gi] = 0; gateb[gi] = 0.f; }

  __shared__ float xs[8 * 1024];
  __shared__ float lg[8][64];
  __shared__ int lcnt[8];
  if (threadIdx.x < 8) lcnt[threadIdx.x] = 0;
  int r0 = blockIdx.x * 8;
  const float4* xg = (const float4*)(x + (size_t)r0 * 1024);
  float4* xs4 = (float4*)xs;
  for (int i = threadIdx.x; i < 2048; i += 256) xs4[i] = xg[i];
  __syncthreads();
  int g = threadIdx.x >> 6, lane = threadIdx.x & 63;
  float a0 = Wc[1024 * 64 + lane], a1 = a0;  // bias-combined row
  const float* x0 = xs + g * 1024;
  const float* x1 = xs + (g + 4) * 1024;
  for (int k = 0; k < 1024; ++k) {
    float w = Wc[(size_t)k * 64 + lane];
    a0 = fmaf(x0[k], w, a0);
    a1 = fmaf(x1[k], w, a1);
  }
  lg[g][lane] = a0; lg[g + 4][lane] = a1;
  __syncthreads();
  if (threadIdx.x < 64) {
    int row = threadIdx.x >> 3, nh = threadIdx.x & 7;
    float l[8];
#pragma unroll
    for (int e = 0; e < 8; ++e) l[e] = lg[row][nh * 8 + e];
    int i1 = 0; float v1 = l[0];
#pragma unroll
    for (int e = 1; e < 8; ++e) if (l[e] > v1) { v1 = l[e]; i1 = e; }
    int i2 = -1; float v2 = -1e30f;
#pragma unroll
    for (int e = 0; e < 8; ++e) if (e != i1 && l[e] > v2) { v2 = l[e]; i2 = e; }
    float g1 = 1.f / (1.f + __expf(v2 - v1));
    float g2 = 1.f - g1;
    size_t t = (size_t)(r0 + row) * 8 + nh;
    tok_e[t * 2] = i1; tok_e[t * 2 + 1] = i2;
    tok_g[t * 2] = g1; tok_g[t * 2 + 1] = g2;
    atomicAdd(&lcnt[i1], 1);
    atomicAdd(&lcnt[i2], 1);
  }
  __syncthreads();
  if (threadIdx.x < 8 && lcnt[threadIdx.x])
    atomicAdd(&ctrl[CTRL_CNT + threadIdx.x], lcnt[threadIdx.x]);
}

// ---------------- assign (unchanged) ----------------
__global__ __launch_bounds__(256) void assign_kernel(
    const int* __restrict__ tok_e, const float* __restrict__ tok_g,
    int* __restrict__ ctrl, int* __restrict__ perm,
    float* __restrict__ gateb, int* __restrict__ tok_slot) {
  __shared__ int lcnt[8], lbase[8];
  if (threadIdx.x < 8) lcnt[threadIdx.x] = 0;
  __syncthreads();
  int t = blockIdx.x * 256 + threadIdx.x;
  int e0 = tok_e[t * 2], e1 = tok_e[t * 2 + 1];
  int p0 = atomicAdd(&lcnt[e0], 1);
  int p1 = atomicAdd(&lcnt[e1], 1);
  __syncthreads();
  if (threadIdx.x < 8)
    lbase[threadIdx.x] = atomicAdd(&ctrl[CTRL_CUR + threadIdx.x], lcnt[threadIdx.x]);
  __syncthreads();
  int off0 = 0, off1 = 0, acc = 0;
#pragma unroll
  for (int i = 0; i < 8; ++i) {
    int cnt = ctrl[CTRL_CNT + i];
    if (i == e0) off0 = acc;
    if (i == e1) off1 = acc;
    acc += (cnt + 127) & ~127;
  }
  int s0 = off0 + lbase[e0] + p0;
  int s1 = off1 + lbase[e1] + p1;
  perm[s0] = t; perm[s1] = t;
  gateb[s0] = tok_g[t * 2]; gateb[s1] = tok_g[t * 2 + 1];
  tok_slot[t * 2] = s0; tok_slot[t * 2 + 1] = s1;
}

// ---------------- GEMM (unchanged) ----------------
template <int OUT_BF16>
__global__ __launch_bounds__(256) void gemm_bt(
    const unsigned short* __restrict__ A, const unsigned short* __restrict__ Bt,
    const float* __restrict__ bias, void* __restrict__ Cout,
    int M, int N, int K) {
  __shared__ unsigned short As[2][64 * 64];
  __shared__ unsigned short Bs[2][128 * 64];
  const int tid = threadIdx.x, lane = tid & 63, wid = tid >> 6;
  const int wr = wid & 1, wc = wid >> 1;
  const int m0 = blockIdx.x * 64, n0 = blockIdx.y * 128;
  const int l15 = lane & 15, lhi = lane >> 4;

  f32x4 acc[2][4];
#pragma unroll
  for (int n = 0; n < 4; ++n) {
    float bv = bias[n0 + wc * 64 + n * 16 + l15];
#pragma unroll
    for (int m = 0; m < 2; ++m) acc[m][n] = (f32x4){bv, bv, bv, bv};
  }

  const int rowi = tid >> 3;
  const int segi = (tid & 7) * 8;
  const int NT = K >> 6;

  auto stage = [&](int buf, int kt) {
    const int k0 = kt * 64;
#pragma unroll
    for (int r = 0; r < 2; ++r)
      gload_lds16(A + (size_t)(m0 + r * 32 + rowi) * K + k0 + segi,
                  &As[buf][r * 2048 + wid * 512]);
#pragma unroll
    for (int r = 0; r < 4; ++r)
      gload_lds16(Bt + (size_t)(n0 + r * 32 + rowi) * K + k0 + segi,
                  &Bs[buf][r * 2048 + wid * 512]);
  };

  stage(0, 0);
  asm volatile("s_waitcnt vmcnt(0)" ::: "memory");
  __syncthreads();
  int cur = 0;
  for (int t = 0; t < NT; ++t) {
    if (t + 1 < NT) stage(cur ^ 1, t + 1);
#pragma unroll
    for (int ks = 0; ks < 64; ks += 32) {
      bf16x8 af[2], bb[4];
#pragma unroll
      for (int m = 0; m < 2; ++m)
        af[m] = *(const bf16x8*)&As[cur][(wr * 32 + m * 16 + l15) * 64 + ks + lhi * 8];
#pragma unroll
      for (int n = 0; n < 4; ++n)
        bb[n] = *(const bf16x8*)&Bs[cur][(wc * 64 + n * 16 + l15) * 64 + ks + lhi * 8];
#pragma unroll
      for (int m = 0; m < 2; ++m)
#pragma unroll
        for (int n = 0; n < 4; ++n)
          acc[m][n] = __builtin_amdgcn_mfma_f32_16x16x32_bf16(af[m], bb[n], acc[m][n], 0, 0, 0);
    }
    asm volatile("s_waitcnt vmcnt(0)" ::: "memory");
    __syncthreads();
    cur ^= 1;
  }
#pragma unroll
  for (int m = 0; m < 2; ++m) {
#pragma unroll
    for (int n = 0; n < 4; ++n) {
      int col = n0 + wc * 64 + n * 16 + l15;
#pragma unroll
      for (int j = 0; j < 4; ++j) {
        int row = m0 + wr * 32 + m * 16 + lhi * 4 + j;
        if (OUT_BF16)
          ((unsigned short*)Cout)[(size_t)row * N + col] = f2bf(acc[m][n][j]);
        else
          ((float*)Cout)[(size_t)row * N + col] = acc[m][n][j];
      }
    }
  }
}

// ---------------- sparse FFN v6: F-split, LDS-staged weights ---------------
// 512 threads = 8 waves. fh = w>>2 (f-half), ws = w&3 (32-slot group).
// Per iter (1 ft = 32 f per fh, 8 iters): stage next W1+W2 chunk (dbuf),
// phase1 (8 MFMA from LDS), gelu*gate in-reg, cvt_pk+permlane, phase2
// (8 MFMA from LDS), vmcnt(0)+barrier. End: fh1 partial y -> LDS fp32
// ([hd][slot], aliased over staging pool), fh0 adds + writes ybuf.
__global__ __launch_bounds__(512, 4) void ffn_sparse_v6(
    const unsigned short* __restrict__ hbf,   // [32768][128]
    const int* __restrict__ ctrl,
    const int* __restrict__ perm,             // [NSLOT]
    const float* __restrict__ gateb,          // [NSLOT]
    const unsigned short* __restrict__ W1F,   // [e][16][8][64][8]
    const float* __restrict__ b1,             // [8][512]
    const unsigned short* __restrict__ W2F,   // [e][16][2][4][64][8]
    const float* __restrict__ b2,             // [8][128]
    unsigned short* __restrict__ ybuf) {      // [NSLOT][128]
  // derive expert + slot base from counts
  int e = -1, slotbase = 0;
  {
    int accT = 0, accS = 0;
#pragma unroll
    for (int i = 0; i < 8; ++i) {
      int cnt = ctrl[CTRL_CNT + i];
      int tiles = (cnt + 127) >> 7;
      if (e < 0 && (int)blockIdx.x < accT + tiles) {
        e = i;
        slotbase = accS + ((int)blockIdx.x - accT) * 128;
      }
      accT += tiles;
      accS += tiles * 128;
    }
  }
  if (e < 0) return;

  // LDS pool: [fh][buf] 8KB W1 chunks (32KB) + [fh][buf] 8KB W2 chunks (32KB)
  // aliased as 64KB fp32 yred[128 hd][128 slot] after the loop.
  __shared__ __align__(16) unsigned short pool[32768];
  unsigned short* W1s = pool;            // (fh*2+buf)*4096
  unsigned short* W2s = pool + 16384;    // (fh*2+buf)*4096
  float* yred = (float*)pool;            // [128][128]

  const int tid = threadIdx.x, l = tid & 63, w = tid >> 6;
  const int l31 = l & 31, lh = l >> 5;
  const int fh = w >> 2, ws = w & 3;
  const int slot = slotbase + ws * 32 + l31;
  const int prow = perm[slot];
  const float gate = gateb[slot];

  // h B-fragments: col=tok(l31), k=hd = kk*16 + lh*8 + j  (held all kernel)
  bf16x8 hreg[8];
  {
    const unsigned short* hsrc = hbf + (size_t)prow * 128 + lh * 8;
#pragma unroll
    for (int kk = 0; kk < 8; ++kk)
      hreg[kk] = *(const bf16x8*)(hsrc + kk * 16);
  }

  const unsigned short* W1e = W1F + (size_t)e * 65536;
  const unsigned short* W2e = W2F + (size_t)e * 65536;
  const float4* b14 = (const float4*)(b1 + (size_t)e * 512);

  auto stage = [&](int buf, int ft) {
#pragma unroll
    for (int r = 0; r < 2; ++r) {
      gload_lds16(W1e + (size_t)ft * 4096 + (size_t)(r * 256 + ws * 64 + l) * 8,
                  W1s + (fh * 2 + buf) * 4096 + (r * 256 + ws * 64) * 8);
      gload_lds16(W2e + (size_t)ft * 4096 + (size_t)(r * 256 + ws * 64 + l) * 8,
                  W2s + (fh * 2 + buf) * 4096 + (r * 256 + ws * 64) * 8);
    }
  };

  stage(0, fh * 8);
  asm volatile("s_waitcnt vmcnt(0)" ::: "memory");
  __syncthreads();

  f32x16 yacc[4] = {};
  int cur = 0;
  for (int it = 0; it < 8; ++it) {
    const int ft = fh * 8 + it;
    if (it < 7) stage(cur ^ 1, ft + 1);
    // phase 1: aacc init = b1, 8-deep MFMA chain from LDS W1 frags
    float4 q0 = b14[ft * 8 + lh],     q1 = b14[ft * 8 + lh + 2];
    float4 q2 = b14[ft * 8 + lh + 4], q3 = b14[ft * 8 + lh + 6];
    f32x16 aacc = {q0.x, q0.y, q0.z, q0.w, q1.x, q1.y, q1.z, q1.w,
                   q2.x, q2.y, q2.z, q2.w, q3.x, q3.y, q3.z, q3.w};
    const unsigned short* W1c = W1s + (fh * 2 + cur) * 4096;
#pragma unroll
    for (int kk = 0; kk < 8; ++kk) {
      bf16x8 a1 = *(const bf16x8*)(W1c + (kk * 64 + l) * 8);
      aacc = __builtin_amdgcn_mfma_f32_32x32x16_bf16(a1, hreg[kk], aacc, 0, 0, 0);
    }
    // gelu(tanh)*gate in-register
    float ge[16];
#pragma unroll
    for (int r = 0; r < 16; ++r) {
      float v = aacc[r];
      float s2 = v * v;
      float q = fmaf(0.1029432f, s2, 2.3022078f);
      float E = exp2f(v * q);
      float rc = __builtin_amdgcn_rcpf(E + 1.f);
      ge[r] = fmaf(-v, rc, v) * gate;
    }
    // pack pairs -> bf16 words; swap halves to form B-frags (k = f)
    unsigned pk[8];
#pragma unroll
    for (int p = 0; p < 8; ++p) {
      unsigned r;
      asm("v_cvt_pk_bf16_f32 %0, %1, %2" : "=v"(r) : "v"(ge[2 * p]), "v"(ge[2 * p + 1]));
      pk[p] = r;
    }
    asm volatile("v_permlane32_swap_b32 %0, %1" : "+v"(pk[0]), "+v"(pk[2]));
    asm volatile("v_permlane32_swap_b32 %0, %1" : "+v"(pk[1]), "+v"(pk[3]));
    asm volatile("v_permlane32_swap_b32 %0, %1" : "+v"(pk[4]), "+v"(pk[6]));
    asm volatile("v_permlane32_swap_b32 %0, %1" : "+v"(pk[5]), "+v"(pk[7]));
    typedef __attribute__((ext_vector_type(4))) unsigned u32x4;
    u32x4 f0 = {pk[0], pk[1], pk[2], pk[3]};
    u32x4 f1 = {pk[4], pk[5], pk[6], pk[7]};
    bf16x8 act0 = __builtin_bit_cast(bf16x8, f0);
    bf16x8 act1 = __builtin_bit_cast(bf16x8, f1);
    // phase 2: yacc[ht] += W2frag @ act (4 indep chains, 2-deep)
    const unsigned short* W2c = W2s + (fh * 2 + cur) * 4096;
#pragma unroll
    for (int ht = 0; ht < 4; ++ht) {
      bf16x8 a20 = *(const bf16x8*)(W2c + (ht * 64 + l) * 8);
      yacc[ht] = __builtin_amdgcn_mfma_f32_32x32x16_bf16(a20, act0, yacc[ht], 0, 0, 0);
      bf16x8 a21 = *(const bf16x8*)(W2c + ((4 + ht) * 64 + l) * 8);
      yacc[ht] = __builtin_amdgcn_mfma_f32_32x32x16_bf16(a21, act1, yacc[ht], 0, 0, 0);
    }
    asm volatile("s_waitcnt vmcnt(0)" ::: "memory");
    __syncthreads();
    cur ^= 1;
  }

  // ---- reduction: fh1 partial -> LDS fp32 [hd][slot] (conflict-free) ----
  const int sl = ws * 32 + l31;
  if (fh == 1) {
#pragma unroll
    for (int ht = 0; ht < 4; ++ht) {
#pragma unroll
      for (int rp = 0; rp < 8; ++rp) {
        int fr = ((2 * rp) & 3) + 8 * (rp >> 1) + 4 * lh;
        int hd = ht * 32 + fr;
        yred[hd * 128 + sl] = yacc[ht][2 * rp];
        yred[(hd + 1) * 128 + sl] = yacc[ht][2 * rp + 1];
      }
    }
  }
  __syncthreads();
  if (fh == 0) {
    const float* b2e = b2 + (size_t)e * 128;
#pragma unroll
    for (int ht = 0; ht < 4; ++ht) {
#pragma unroll
      for (int rp = 0; rp < 8; ++rp) {
        int fr = ((2 * rp) & 3) + 8 * (rp >> 1) + 4 * lh;
        int hd = ht * 32 + fr;
        float2 bb2 = *(const float2*)&b2e[hd];
        float v0 = yacc[ht][2 * rp] + yred[hd * 128 + sl] + gate * bb2.x;
        float v1 = yacc[ht][2 * rp + 1] + yred[(hd + 1) * 128 + sl] + gate * bb2.y;
        unsigned pw;
        asm("v_cvt_pk_bf16_f32 %0, %1, %2" : "=v"(pw) : "v"(v0), "v"(v1));
        *(unsigned*)(ybuf + (size_t)slot * 128 + hd) = pw;
      }
    }
  }
}

// ---------------- combine (unchanged) ----------------
__global__ __launch_bounds__(256) void combine_kernel(
    const unsigned short* __restrict__ ybuf, const int* __restrict__ tok_slot,
    unsigned short* __restrict__ moebf) {
  int t = blockIdx.x * 8 + (threadIdx.x >> 5);
  int c = (threadIdx.x & 31) * 4;
  int s0 = tok_slot[t * 2], s1 = tok_slot[t * 2 + 1];
  u16x4 a = *(const u16x4*)(ybuf + (size_t)s0 * 128 + c);
  u16x4 b = *(const u16x4*)(ybuf + (size_t)s1 * 128 + c);
  u16x4 o;
#pragma unroll
  for (int i = 0; i < 4; ++i) o[i] = f2bf(bf2f(a[i]) + bf2f(b[i]));
  *(u16x4*)(moebf + (size_t)t * 128 + c) = o;
}

// ---------------------------------------------------------------------------
extern "C" void kernel_launch(void* const* d_in, const int* in_sizes, int n_in,
                              void* d_out, int out_size, void* d_ws, size_t ws_size,
                              hipStream_t stream) {
  const float* x       = (const float*)d_in[0];
  const float* W_mh    = (const float*)d_in[1];
  const float* b_mh    = (const float*)d_in[2];
  const float* W_merge = (const float*)d_in[3];
  const float* b_merge = (const float*)d_in[4];
  const float* W_rout  = (const float*)d_in[5];
  const float* W1      = (const float*)d_in[6];
  const float* b1      = (const float*)d_in[7];
  const float* W2      = (const float*)d_in[8];
  const float* b2      = (const float*)d_in[9];
  float* out = (float*)d_out;

  char* ws = (char*)d_ws;
  size_t off = 0;
  auto alloc = [&](size_t bytes) {
    void* p = ws + off;
    off = (off + bytes + 255) & ~(size_t)255;
    return p;
  };
  unsigned short* x_bf  = (unsigned short*)alloc((size_t)4096 * 1024 * 2);
  unsigned short* Wmh_t = (unsigned short*)alloc((size_t)1024 * 1024 * 2);
  unsigned short* Wmg_t = (unsigned short*)alloc((size_t)1024 * 1024 * 2);
  unsigned short* W1F   = (unsigned short*)alloc((size_t)8 * 512 * 128 * 2);
  unsigned short* W2F   = (unsigned short*)alloc((size_t)8 * 512 * 128 * 2);
  unsigned short* h_bf  = (unsigned short*)alloc((size_t)4096 * 1024 * 2);
  unsigned short* moebf = (unsigned short*)alloc((size_t)4096 * 1024 * 2);
  unsigned short* ybuf  = (unsigned short*)alloc((size_t)NSLOT * 128 * 2);
  float* Wc             = (float*)alloc((size_t)1025 * 64 * 4);
  int*   ctrl           = (int*)alloc(4096);
  int*   tok_e          = (int*)alloc((size_t)32768 * 2 * 4);
  float* tok_g          = (float*)alloc((size_t)32768 * 2 * 4);
  int*   tok_slot       = (int*)alloc((size_t)32768 * 2 * 4);
  int*   perm           = (int*)alloc((size_t)NSLOT * 4);
  float* gateb          = (float*)alloc((size_t)NSLOT * 4);

  prep_all<<<3841, 256, 0, stream>>>(x, x_bf, W_mh, Wmh_t, W_merge, Wmg_t,
                                     W1, W2, W1F, W2F, b_mh, W_rout, Wc, ctrl);
  router_kernel<<<512, 256, 0, stream>>>(x, Wc, tok_e, tok_g, ctrl, perm, gateb);
  assign_kernel<<<128, 256, 0, stream>>>(tok_e, tok_g, ctrl, perm, gateb, tok_slot);
  gemm_bt<1><<<dim3(64, 8), 256, 0, stream>>>(x_bf, Wmh_t, b_mh, (void*)h_bf, 4096, 1024, 1024);
  ffn_sparse_v6<<<NTILE_MAX, 512, 0, stream>>>(h_bf, ctrl, perm, gateb, W1F, b1, W2F, b2, ybuf);
  combine_kernel<<<4096, 256, 0, stream>>>(ybuf, tok_slot, moebf);
  gemm_bt<0><<<dim3(64, 8), 256, 0, stream>>>(moebf, Wmg_t, b_merge, (void*)out, 4096, 1024, 1024);
}

// Round 7
// 162.958 us; speedup vs baseline: 1.0842x; 1.0842x over previous
//
#include <hip/hip_runtime.h>

// ---------------------------------------------------------------------------
// MH-MoE, top-2 sparse dispatch, in-register expert FFN.
// B=2 S=2048 H=1024 NH=8 HD=128 T=16384 (32768 tokens) E=8 K=2 F=512
// FFN v7: v3 skeleton (LDS-dbuf weight staging, 4 waves, 128 slots/block)
// with 2 f-tiles per iteration (8 iters, 32 MFMA/iter), gate moved to the
// epilogue, s_setprio around MFMA clusters. Act stays in registers
// (cvt_pk_bf16 + permlane32_swap).
// ---------------------------------------------------------------------------

typedef __attribute__((ext_vector_type(8))) short bf16x8;
typedef __attribute__((ext_vector_type(4))) float f32x4;
typedef __attribute__((ext_vector_type(16))) float f32x16;
typedef __attribute__((ext_vector_type(4))) unsigned short u16x4;

constexpr int NSLOT = 66560;      // 520 tiles * 128 slots
constexpr int NTILE_MAX = 520;
#define CTRL_CNT 0
#define CTRL_CUR 8

__device__ __forceinline__ unsigned short f2bf(float x) {
  unsigned int u = __float_as_uint(x);
  return (unsigned short)((u + 0x7FFFu + ((u >> 16) & 1u)) >> 16);
}
__device__ __forceinline__ float bf2f(unsigned short u) {
  return __uint_as_float(((unsigned int)u) << 16);
}
__device__ __forceinline__ void gload_lds16(const void* g, void* l) {
  __builtin_amdgcn_global_load_lds(
      (const __attribute__((address_space(1))) unsigned int*)g,
      (__attribute__((address_space(3))) unsigned int*)l, 16, 0, 0);
}

// ---------------- fused prep (unchanged) ----------------
__global__ __launch_bounds__(256) void prep_all(
    const float* __restrict__ x, unsigned short* __restrict__ x_bf,
    const float* __restrict__ Wmh, unsigned short* __restrict__ Wmh_t,
    const float* __restrict__ Wmg, unsigned short* __restrict__ Wmg_t,
    const float* __restrict__ W1, const float* __restrict__ W2,
    unsigned short* __restrict__ W1F, unsigned short* __restrict__ W2F,
    const float* __restrict__ bmh, const float* __restrict__ Wr,
    float* __restrict__ Wc, int* __restrict__ ctrl) {
  __shared__ float smem[2048];
  const int bid = blockIdx.x, tid = threadIdx.x;
  if (bid < 1024) {
    if (bid == 0 && tid < 16) ctrl[tid] = 0;
    int i = bid * 256 + tid;
    const int n4 = 4096 * 1024 / 4, stride = 1024 * 256;
    for (; i < n4; i += stride) {
      float4 v = ((const float4*)x)[i];
      u16x4 o;
      o.x = f2bf(v.x); o.y = f2bf(v.y); o.z = f2bf(v.z); o.w = f2bf(v.w);
      ((u16x4*)x_bf)[i] = o;
    }
  } else if (bid < 3072) {
    const int b = bid - 1024;
    const float* src = (b < 1024) ? Wmh : Wmg;
    unsigned short* dst = (b < 1024) ? Wmh_t : Wmg_t;
    const int bb = b & 1023;
    const int c0 = (bb & 31) * 32, r0 = (bb >> 5) * 32;
    const int tx = tid & 31, ty = tid >> 5;
    float (*tile)[33] = (float(*)[33])smem;
    for (int i = ty; i < 32; i += 8)
      tile[i][tx] = src[(size_t)(r0 + i) * 1024 + c0 + tx];
    __syncthreads();
    for (int i = ty; i < 32; i += 8)
      dst[(size_t)(c0 + i) * 1024 + r0 + tx] = f2bf(tile[tx][i]);
  } else if (bid < 3584) {
    const int jid = (bid - 3072) * 4 + (tid >> 6);   // 0..2047
    const int l = tid & 63;
    const int is2 = jid >= 1024;
    const int bj = is2 ? jid - 1024 : jid;
    const float* src;
    int C;
    if (!is2) {
      int kk = bj & 7, ft = (bj >> 3) & 15, e = bj >> 7;
      src = W1 + (size_t)e * 65536 + (size_t)(kk * 16) * 512 + ft * 32;
      C = 512;
    } else {
      int sht = bj & 7, ft = (bj >> 3) & 15, e = bj >> 7;
      src = W2 + (size_t)e * 65536 + (size_t)(ft * 32 + (sht >> 2) * 16) * 128 + (sht & 3) * 32;
      C = 128;
    }
    float* tile = smem + (tid >> 6) * 512;   // [16][32]
#pragma unroll
    for (int r = 0; r < 8; ++r) {
      int i = l + 64 * r;
      tile[(i >> 5) * 32 + (i & 31)] = src[(size_t)(i >> 5) * C + (i & 31)];
    }
    __syncthreads();
    int l31 = l & 31, lh = l >> 5;
    bf16x8 v;
#pragma unroll
    for (int j = 0; j < 8; ++j) v[j] = (short)f2bf(tile[(lh * 8 + j) * 32 + l31]);
    unsigned short* dst = is2 ? W2F : W1F;
    *(bf16x8*)(dst + ((size_t)bj * 64 + l) * 8) = v;
  } else {
    const int r = (bid - 3584) * 4 + (tid >> 6);
    if (r > 1024) return;
    const int l = tid & 63;
    const float* src = (r < 1024) ? (Wmh + (size_t)r * 1024) : bmh;
    int nh = l >> 3, e = l & 7;
    float acc = 0.f;
    for (int d = 0; d < 128; ++d) acc = fmaf(src[nh * 128 + d], Wr[d * 8 + e], acc);
    Wc[(size_t)r * 64 + l] = acc;
  }
}

// ---------------- router (unchanged) ----------------
__global__ __launch_bounds__(256) void router_kernel(
    const float* __restrict__ x, const float* __restrict__ Wc,
    int* __restrict__ tok_e, float* __restrict__ tok_g,
    int* __restrict__ ctrl, int* __restrict__ perm, float* __restrict__ gateb) {
  int gi = blockIdx.x * 256 + threadIdx.x;
  if (gi < NSLOT) { perm[gi] = 0; gateb[gi] = 0.f; }

  __shared__ float xs[8 * 1024];
  __shared__ float lg[8][64];
  __shared__ int lcnt[8];
  if (threadIdx.x < 8) lcnt[threadIdx.x] = 0;
  int r0 = blockIdx.x * 8;
  const float4* xg = (const float4*)(x + (size_t)r0 * 1024);
  float4* xs4 = (float4*)xs;
  for (int i = threadIdx.x; i < 2048; i += 256) xs4[i] = xg[i];
  __syncthreads();
  int g = threadIdx.x >> 6, lane = threadIdx.x & 63;
  float a0 = Wc[1024 * 64 + lane], a1 = a0;  // bias-combined row
  const float* x0 = xs + g * 1024;
  const float* x1 = xs + (g + 4) * 1024;
  for (int k = 0; k < 1024; ++k) {
    float w = Wc[(size_t)k * 64 + lane];
    a0 = fmaf(x0[k], w, a0);
    a1 = fmaf(x1[k], w, a1);
  }
  lg[g][lane] = a0; lg[g + 4][lane] = a1;
  __syncthreads();
  if (threadIdx.x < 64) {
    int row = threadIdx.x >> 3, nh = threadIdx.x & 7;
    float l[8];
#pragma unroll
    for (int e = 0; e < 8; ++e) l[e] = lg[row][nh * 8 + e];
    int i1 = 0; float v1 = l[0];
#pragma unroll
    for (int e = 1; e < 8; ++e) if (l[e] > v1) { v1 = l[e]; i1 = e; }
    int i2 = -1; float v2 = -1e30f;
#pragma unroll
    for (int e = 0; e < 8; ++e) if (e != i1 && l[e] > v2) { v2 = l[e]; i2 = e; }
    float g1 = 1.f / (1.f + __expf(v2 - v1));
    float g2 = 1.f - g1;
    size_t t = (size_t)(r0 + row) * 8 + nh;
    tok_e[t * 2] = i1; tok_e[t * 2 + 1] = i2;
    tok_g[t * 2] = g1; tok_g[t * 2 + 1] = g2;
    atomicAdd(&lcnt[i1], 1);
    atomicAdd(&lcnt[i2], 1);
  }
  __syncthreads();
  if (threadIdx.x < 8 && lcnt[threadIdx.x])
    atomicAdd(&ctrl[CTRL_CNT + threadIdx.x], lcnt[threadIdx.x]);
}

// ---------------- assign (unchanged) ----------------
__global__ __launch_bounds__(256) void assign_kernel(
    const int* __restrict__ tok_e, const float* __restrict__ tok_g,
    int* __restrict__ ctrl, int* __restrict__ perm,
    float* __restrict__ gateb, int* __restrict__ tok_slot) {
  __shared__ int lcnt[8], lbase[8];
  if (threadIdx.x < 8) lcnt[threadIdx.x] = 0;
  __syncthreads();
  int t = blockIdx.x * 256 + threadIdx.x;
  int e0 = tok_e[t * 2], e1 = tok_e[t * 2 + 1];
  int p0 = atomicAdd(&lcnt[e0], 1);
  int p1 = atomicAdd(&lcnt[e1], 1);
  __syncthreads();
  if (threadIdx.x < 8)
    lbase[threadIdx.x] = atomicAdd(&ctrl[CTRL_CUR + threadIdx.x], lcnt[threadIdx.x]);
  __syncthreads();
  int off0 = 0, off1 = 0, acc = 0;
#pragma unroll
  for (int i = 0; i < 8; ++i) {
    int cnt = ctrl[CTRL_CNT + i];
    if (i == e0) off0 = acc;
    if (i == e1) off1 = acc;
    acc += (cnt + 127) & ~127;
  }
  int s0 = off0 + lbase[e0] + p0;
  int s1 = off1 + lbase[e1] + p1;
  perm[s0] = t; perm[s1] = t;
  gateb[s0] = tok_g[t * 2]; gateb[s1] = tok_g[t * 2 + 1];
  tok_slot[t * 2] = s0; tok_slot[t * 2 + 1] = s1;
}

// ---------------- GEMM (unchanged) ----------------
template <int OUT_BF16>
__global__ __launch_bounds__(256) void gemm_bt(
    const unsigned short* __restrict__ A, const unsigned short* __restrict__ Bt,
    const float* __restrict__ bias, void* __restrict__ Cout,
    int M, int N, int K) {
  __shared__ unsigned short As[2][64 * 64];
  __shared__ unsigned short Bs[2][128 * 64];
  const int tid = threadIdx.x, lane = tid & 63, wid = tid >> 6;
  const int wr = wid & 1, wc = wid >> 1;
  const int m0 = blockIdx.x * 64, n0 = blockIdx.y * 128;
  const int l15 = lane & 15, lhi = lane >> 4;

  f32x4 acc[2][4];
#pragma unroll
  for (int n = 0; n < 4; ++n) {
    float bv = bias[n0 + wc * 64 + n * 16 + l15];
#pragma unroll
    for (int m = 0; m < 2; ++m) acc[m][n] = (f32x4){bv, bv, bv, bv};
  }

  const int rowi = tid >> 3;
  const int segi = (tid & 7) * 8;
  const int NT = K >> 6;

  auto stage = [&](int buf, int kt) {
    const int k0 = kt * 64;
#pragma unroll
    for (int r = 0; r < 2; ++r)
      gload_lds16(A + (size_t)(m0 + r * 32 + rowi) * K + k0 + segi,
                  &As[buf][r * 2048 + wid * 512]);
#pragma unroll
    for (int r = 0; r < 4; ++r)
      gload_lds16(Bt + (size_t)(n0 + r * 32 + rowi) * K + k0 + segi,
                  &Bs[buf][r * 2048 + wid * 512]);
  };

  stage(0, 0);
  asm volatile("s_waitcnt vmcnt(0)" ::: "memory");
  __syncthreads();
  int cur = 0;
  for (int t = 0; t < NT; ++t) {
    if (t + 1 < NT) stage(cur ^ 1, t + 1);
#pragma unroll
    for (int ks = 0; ks < 64; ks += 32) {
      bf16x8 af[2], bb[4];
#pragma unroll
      for (int m = 0; m < 2; ++m)
        af[m] = *(const bf16x8*)&As[cur][(wr * 32 + m * 16 + l15) * 64 + ks + lhi * 8];
#pragma unroll
      for (int n = 0; n < 4; ++n)
        bb[n] = *(const bf16x8*)&Bs[cur][(wc * 64 + n * 16 + l15) * 64 + ks + lhi * 8];
#pragma unroll
      for (int m = 0; m < 2; ++m)
#pragma unroll
        for (int n = 0; n < 4; ++n)
          acc[m][n] = __builtin_amdgcn_mfma_f32_16x16x32_bf16(af[m], bb[n], acc[m][n], 0, 0, 0);
    }
    asm volatile("s_waitcnt vmcnt(0)" ::: "memory");
    __syncthreads();
    cur ^= 1;
  }
#pragma unroll
  for (int m = 0; m < 2; ++m) {
#pragma unroll
    for (int n = 0; n < 4; ++n) {
      int col = n0 + wc * 64 + n * 16 + l15;
#pragma unroll
      for (int j = 0; j < 4; ++j) {
        int row = m0 + wr * 32 + m * 16 + lhi * 4 + j;
        if (OUT_BF16)
          ((unsigned short*)Cout)[(size_t)row * N + col] = f2bf(acc[m][n][j]);
        else
          ((float*)Cout)[(size_t)row * N + col] = acc[m][n][j];
      }
    }
  }
}

// ---------------- sparse FFN v7: LDS dbuf, 2 f-tiles/iter, setprio ---------
// Block: 128 slots, 4 waves (32 slots each). Per iter (2 ft = 64 f, 8 iters):
//   stage next 32KB (W1+W2 x 2ft, dbuf); phase1: 2 indep 8-deep MFMA chains;
//   gelu in-reg (no gate); cvt_pk+permlane -> 4 act B-frags; phase2: 4 indep
//   4-deep chains; vmcnt(0)+barrier. Gate applied in epilogue.
__global__ __launch_bounds__(256, 2) void ffn_sparse_v7(
    const unsigned short* __restrict__ hbf,   // [32768][128]
    const int* __restrict__ ctrl,
    const int* __restrict__ perm,             // [NSLOT]
    const float* __restrict__ gateb,          // [NSLOT]
    const unsigned short* __restrict__ W1F,   // [e][16][8][64][8]
    const float* __restrict__ b1,             // [8][512]
    const unsigned short* __restrict__ W2F,   // [e][16][2][4][64][8]
    const float* __restrict__ b2,             // [8][128]
    unsigned short* __restrict__ ybuf) {      // [NSLOT][128]
  // derive expert + slot base from counts
  int e = -1, slotbase = 0;
  {
    int accT = 0, accS = 0;
#pragma unroll
    for (int i = 0; i < 8; ++i) {
      int cnt = ctrl[CTRL_CNT + i];
      int tiles = (cnt + 127) >> 7;
      if (e < 0 && (int)blockIdx.x < accT + tiles) {
        e = i;
        slotbase = accS + ((int)blockIdx.x - accT) * 128;
      }
      accT += tiles;
      accS += tiles * 128;
    }
  }
  if (e < 0) return;

  __shared__ __align__(16) unsigned short W1c[2][2][4096];
  __shared__ __align__(16) unsigned short W2c[2][2][4096];

  const int tid = threadIdx.x, l = tid & 63, w = tid >> 6;
  const int l31 = l & 31, lh = l >> 5;
  const int slot = slotbase + w * 32 + l31;
  const int prow = perm[slot];
  const float gate = gateb[slot];

  // h B-fragments: col=tok(l31), k=hd = kk*16 + lh*8 + j  (held all kernel)
  bf16x8 hreg[8];
  {
    const unsigned short* hsrc = hbf + (size_t)prow * 128 + lh * 8;
#pragma unroll
    for (int kk = 0; kk < 8; ++kk)
      hreg[kk] = *(const bf16x8*)(hsrc + kk * 16);
  }

  const unsigned short* W1e = W1F + (size_t)e * 65536;
  const unsigned short* W2e = W2F + (size_t)e * 65536;
  const float4* b14 = (const float4*)(b1 + (size_t)e * 512);

  auto stage = [&](int buf, int it) {
#pragma unroll
    for (int f2 = 0; f2 < 2; ++f2) {
      const int ft = it * 2 + f2;
#pragma unroll
      for (int r = 0; r < 2; ++r) {
        gload_lds16(W1e + (size_t)ft * 4096 + (size_t)(r * 256 + tid) * 8,
                    &W1c[buf][f2][r * 2048 + w * 512]);
        gload_lds16(W2e + (size_t)ft * 4096 + (size_t)(r * 256 + tid) * 8,
                    &W2c[buf][f2][r * 2048 + w * 512]);
      }
    }
  };

  stage(0, 0);
  asm volatile("s_waitcnt vmcnt(0)" ::: "memory");
  __syncthreads();

  f32x16 yacc[4] = {};
  int cur = 0;
  for (int it = 0; it < 8; ++it) {
    const int ft0 = it * 2, ft1 = it * 2 + 1;
    if (it < 7) stage(cur ^ 1, it + 1);
    // ---- phase 1: two independent 8-deep chains (one per ft) ----
    float4 p0 = b14[ft0 * 8 + lh],     p1 = b14[ft0 * 8 + lh + 2];
    float4 p2 = b14[ft0 * 8 + lh + 4], p3 = b14[ft0 * 8 + lh + 6];
    float4 q0 = b14[ft1 * 8 + lh],     q1 = b14[ft1 * 8 + lh + 2];
    float4 q2 = b14[ft1 * 8 + lh + 4], q3 = b14[ft1 * 8 + lh + 6];
    f32x16 a0 = {p0.x, p0.y, p0.z, p0.w, p1.x, p1.y, p1.z, p1.w,
                 p2.x, p2.y, p2.z, p2.w, p3.x, p3.y, p3.z, p3.w};
    f32x16 a1 = {q0.x, q0.y, q0.z, q0.w, q1.x, q1.y, q1.z, q1.w,
                 q2.x, q2.y, q2.z, q2.w, q3.x, q3.y, q3.z, q3.w};
    __builtin_amdgcn_s_setprio(1);
#pragma unroll
    for (int kk = 0; kk < 8; ++kk) {
      bf16x8 w10 = *(const bf16x8*)&W1c[cur][0][(kk * 64 + l) * 8];
      bf16x8 w11 = *(const bf16x8*)&W1c[cur][1][(kk * 64 + l) * 8];
      a0 = __builtin_amdgcn_mfma_f32_32x32x16_bf16(w10, hreg[kk], a0, 0, 0, 0);
      a1 = __builtin_amdgcn_mfma_f32_32x32x16_bf16(w11, hreg[kk], a1, 0, 0, 0);
    }
    __builtin_amdgcn_s_setprio(0);
    // ---- gelu(tanh) in-register (gate deferred to epilogue) ----
    float ge0[16], ge1[16];
#pragma unroll
    for (int r = 0; r < 16; ++r) {
      float v = a0[r];
      float s2 = v * v;
      float q = fmaf(0.1029432f, s2, 2.3022078f);
      float E = exp2f(v * q);
      float rc = __builtin_amdgcn_rcpf(E + 1.f);
      ge0[r] = fmaf(-v, rc, v);
      float v1 = a1[r];
      float s21 = v1 * v1;
      float q1v = fmaf(0.1029432f, s21, 2.3022078f);
      float E1 = exp2f(v1 * q1v);
      float rc1 = __builtin_amdgcn_rcpf(E1 + 1.f);
      ge1[r] = fmaf(-v1, rc1, v1);
    }
    // ---- pack + permlane32_swap -> B-frags (k = f within ft tile) ----
    unsigned pk0[8], pk1[8];
#pragma unroll
    for (int p = 0; p < 8; ++p) {
      unsigned r0v, r1v;
      asm("v_cvt_pk_bf16_f32 %0, %1, %2" : "=v"(r0v) : "v"(ge0[2 * p]), "v"(ge0[2 * p + 1]));
      asm("v_cvt_pk_bf16_f32 %0, %1, %2" : "=v"(r1v) : "v"(ge1[2 * p]), "v"(ge1[2 * p + 1]));
      pk0[p] = r0v; pk1[p] = r1v;
    }
    asm volatile("v_permlane32_swap_b32 %0, %1" : "+v"(pk0[0]), "+v"(pk0[2]));
    asm volatile("v_permlane32_swap_b32 %0, %1" : "+v"(pk0[1]), "+v"(pk0[3]));
    asm volatile("v_permlane32_swap_b32 %0, %1" : "+v"(pk0[4]), "+v"(pk0[6]));
    asm volatile("v_permlane32_swap_b32 %0, %1" : "+v"(pk0[5]), "+v"(pk0[7]));
    asm volatile("v_permlane32_swap_b32 %0, %1" : "+v"(pk1[0]), "+v"(pk1[2]));
    asm volatile("v_permlane32_swap_b32 %0, %1" : "+v"(pk1[1]), "+v"(pk1[3]));
    asm volatile("v_permlane32_swap_b32 %0, %1" : "+v"(pk1[4]), "+v"(pk1[6]));
    asm volatile("v_permlane32_swap_b32 %0, %1" : "+v"(pk1[5]), "+v"(pk1[7]));
    typedef __attribute__((ext_vector_type(4))) unsigned u32x4;
    u32x4 f00 = {pk0[0], pk0[1], pk0[2], pk0[3]};
    u32x4 f01 = {pk0[4], pk0[5], pk0[6], pk0[7]};
    u32x4 f10 = {pk1[0], pk1[1], pk1[2], pk1[3]};
    u32x4 f11 = {pk1[4], pk1[5], pk1[6], pk1[7]};
    bf16x8 act00 = __builtin_bit_cast(bf16x8, f00);
    bf16x8 act01 = __builtin_bit_cast(bf16x8, f01);
    bf16x8 act10 = __builtin_bit_cast(bf16x8, f10);
    bf16x8 act11 = __builtin_bit_cast(bf16x8, f11);
    // ---- phase 2: 4 independent ht chains, 4-deep ----
    __builtin_amdgcn_s_setprio(1);
#pragma unroll
    for (int ht = 0; ht < 4; ++ht) {
      bf16x8 b00 = *(const bf16x8*)&W2c[cur][0][(ht * 64 + l) * 8];
      bf16x8 b01 = *(const bf16x8*)&W2c[cur][0][((4 + ht) * 64 + l) * 8];
      bf16x8 b10 = *(const bf16x8*)&W2c[cur][1][(ht * 64 + l) * 8];
      bf16x8 b11 = *(const bf16x8*)&W2c[cur][1][((4 + ht) * 64 + l) * 8];
      yacc[ht] = __builtin_amdgcn_mfma_f32_32x32x16_bf16(b00, act00, yacc[ht], 0, 0, 0);
      yacc[ht] = __builtin_amdgcn_mfma_f32_32x32x16_bf16(b01, act01, yacc[ht], 0, 0, 0);
      yacc[ht] = __builtin_amdgcn_mfma_f32_32x32x16_bf16(b10, act10, yacc[ht], 0, 0, 0);
      yacc[ht] = __builtin_amdgcn_mfma_f32_32x32x16_bf16(b11, act11, yacc[ht], 0, 0, 0);
    }
    __builtin_amdgcn_s_setprio(0);
    asm volatile("s_waitcnt vmcnt(0)" ::: "memory");
    __syncthreads();
    cur ^= 1;
  }
  // epilogue: gate*(y + b2) -> bf16 pairs -> 4B stores (col = own token)
  const float* b2e = b2 + (size_t)e * 128;
#pragma unroll
  for (int ht = 0; ht < 4; ++ht) {
#pragma unroll
    for (int rp = 0; rp < 8; ++rp) {
      int fr = ((2 * rp) & 3) + 8 * (rp >> 1) + 4 * lh;
      int hd = ht * 32 + fr;
      float2 bb2 = *(const float2*)&b2e[hd];
      float v0 = gate * (yacc[ht][2 * rp] + bb2.x);
      float v1 = gate * (yacc[ht][2 * rp + 1] + bb2.y);
      unsigned pw;
      asm("v_cvt_pk_bf16_f32 %0, %1, %2" : "=v"(pw) : "v"(v0), "v"(v1));
      *(unsigned*)(ybuf + (size_t)slot * 128 + hd) = pw;
    }
  }
}

// ---------------- combine (unchanged) ----------------
__global__ __launch_bounds__(256) void combine_kernel(
    const unsigned short* __restrict__ ybuf, const int* __restrict__ tok_slot,
    unsigned short* __restrict__ moebf) {
  int t = blockIdx.x * 8 + (threadIdx.x >> 5);
  int c = (threadIdx.x & 31) * 4;
  int s0 = tok_slot[t * 2], s1 = tok_slot[t * 2 + 1];
  u16x4 a = *(const u16x4*)(ybuf + (size_t)s0 * 128 + c);
  u16x4 b = *(const u16x4*)(ybuf + (size_t)s1 * 128 + c);
  u16x4 o;
#pragma unroll
  for (int i = 0; i < 4; ++i) o[i] = f2bf(bf2f(a[i]) + bf2f(b[i]));
  *(u16x4*)(moebf + (size_t)t * 128 + c) = o;
}

// ---------------------------------------------------------------------------
extern "C" void kernel_launch(void* const* d_in, const int* in_sizes, int n_in,
                              void* d_out, int out_size, void* d_ws, size_t ws_size,
                              hipStream_t stream) {
  const float* x       = (const float*)d_in[0];
  const float* W_mh    = (const float*)d_in[1];
  const float* b_mh    = (const float*)d_in[2];
  const float* W_merge = (const float*)d_in[3];
  const float* b_merge = (const float*)d_in[4];
  const float* W_rout  = (const float*)d_in[5];
  const float* W1      = (const float*)d_in[6];
  const float* b1      = (const float*)d_in[7];
  const float* W2      = (const float*)d_in[8];
  const float* b2      = (const float*)d_in[9];
  float* out = (float*)d_out;

  char* ws = (char*)d_ws;
  size_t off = 0;
  auto alloc = [&](size_t bytes) {
    void* p = ws + off;
    off = (off + bytes + 255) & ~(size_t)255;
    return p;
  };
  unsigned short* x_bf  = (unsigned short*)alloc((size_t)4096 * 1024 * 2);
  unsigned short* Wmh_t = (unsigned short*)alloc((size_t)1024 * 1024 * 2);
  unsigned short* Wmg_t = (unsigned short*)alloc((size_t)1024 * 1024 * 2);
  unsigned short* W1F   = (unsigned short*)alloc((size_t)8 * 512 * 128 * 2);
  unsigned short* W2F   = (unsigned short*)alloc((size_t)8 * 512 * 128 * 2);
  unsigned short* h_bf  = (unsigned short*)alloc((size_t)4096 * 1024 * 2);
  unsigned short* moebf = (unsigned short*)alloc((size_t)4096 * 1024 * 2);
  unsigned short* ybuf  = (unsigned short*)alloc((size_t)NSLOT * 128 * 2);
  float* Wc             = (float*)alloc((size_t)1025 * 64 * 4);
  int*   ctrl           = (int*)alloc(4096);
  int*   tok_e          = (int*)alloc((size_t)32768 * 2 * 4);
  float* tok_g          = (float*)alloc((size_t)32768 * 2 * 4);
  int*   tok_slot       = (int*)alloc((size_t)32768 * 2 * 4);
  int*   perm           = (int*)alloc((size_t)NSLOT * 4);
  float* gateb          = (float*)alloc((size_t)NSLOT * 4);

  prep_all<<<3841, 256, 0, stream>>>(x, x_bf, W_mh, Wmh_t, W_merge, Wmg_t,
                                     W1, W2, W1F, W2F, b_mh, W_rout, Wc, ctrl);
  router_kernel<<<512, 256, 0, stream>>>(x, Wc, tok_e, tok_g, ctrl, perm, gateb);
  assign_kernel<<<128, 256, 0, stream>>>(tok_e, tok_g, ctrl, perm, gateb, tok_slot);
  gemm_bt<1><<<dim3(64, 8), 256, 0, stream>>>(x_bf, Wmh_t, b_mh, (void*)h_bf, 4096, 1024, 1024);
  ffn_sparse_v7<<<NTILE_MAX, 256, 0, stream>>>(h_bf, ctrl, perm, gateb, W1F, b1, W2F, b2, ybuf);
  combine_kernel<<<4096, 256, 0, stream>>>(ybuf, tok_slot, moebf);
  gemm_bt<0><<<dim3(64, 8), 256, 0, stream>>>(moebf, Wmg_t, b_merge, (void*)out, 4096, 1024, 1024);
}